// Round 1
// baseline (311.685 us; speedup 1.0000x reference)
//
#include <hip/hip_runtime.h>
#include <stdint.h>

#define TPB 256
#define BM 64
#define CTXD 256
#define HID 128
#define G3 384
#define TSTEPS 48
#define DTC (1.0f/30.0f)

typedef short short8 __attribute__((ext_vector_type(8)));
typedef float f32x4 __attribute__((ext_vector_type(4)));
typedef float f32x2 __attribute__((ext_vector_type(2)));

// LDS layout (bytes)
#define OFF_WHH 0        // W_hh bf16 [384][128] swizzled, stride 256
#define OFF_W1  98304    // W1  bf16 [64][128] swizzled, stride 256
#define OFF_H   114688   // 2x h bf16 [64][128] (16384 each); phase A: ctx bf16 [64][256] stride 512
#define OFF_B1  147456   // b1 fp32 [64]
#define OFF_W2  147712   // W2 packed fp32 [64][2]
#define LDS_BYTES 148224

__device__ __forceinline__ unsigned short f2bf(float f) {
    union { float f; uint32_t u; } v; v.f = f;
    uint32_t r = v.u + 0x7FFFu + ((v.u >> 16) & 1u);
    return (unsigned short)(r >> 16);
}
__device__ __forceinline__ uint32_t pk2bf(float a, float b) {
    return (uint32_t)f2bf(a) | ((uint32_t)f2bf(b) << 16);
}
__device__ __forceinline__ float fsigm(float x) {
    return __builtin_amdgcn_rcpf(1.0f + __expf(-x));
}
__device__ __forceinline__ float ftanhf(float x) {
    return fmaf(-2.0f, __builtin_amdgcn_rcpf(1.0f + __expf(2.0f * x)), 1.0f);
}

__global__ __launch_bounds__(TPB, 1)
void dd_kernel(const float* __restrict__ ctx, const float* __restrict__ lv,
               const float* __restrict__ Winit, const float* __restrict__ binit,
               const float* __restrict__ Wih, const float* __restrict__ bih,
               const float* __restrict__ Whh, const float* __restrict__ bhh,
               const float* __restrict__ W1, const float* __restrict__ b1,
               const float* __restrict__ W2, const float* __restrict__ b2,
               float* __restrict__ out)
{
    extern __shared__ char smem[];
    const int tid  = threadIdx.x;
    const int w    = tid >> 6;          // wave 0..3
    const int lane = tid & 63;
    const int g    = (lane >> 4) & 3;   // 16-lane group
    const int l15  = lane & 15;
    const int row0 = blockIdx.x * BM;

    // ---------------- stage weights / ctx into LDS (bf16, swizzled) ----------------
    for (int p = tid; p < G3 * (HID / 2); p += TPB) {
        int u = p >> 6, kp = p & 63;
        f32x2 v = *(const f32x2*)(Whh + u * HID + 2 * kp);
        *(uint32_t*)(smem + OFF_WHH + u * 256 + ((4 * kp) ^ ((u & 7) << 4))) = pk2bf(v.x, v.y);
    }
    for (int p = tid; p < 64 * (HID / 2); p += TPB) {
        int u = p >> 6, kp = p & 63;
        f32x2 v = *(const f32x2*)(W1 + u * HID + 2 * kp);
        *(uint32_t*)(smem + OFF_W1 + u * 256 + ((4 * kp) ^ ((u & 7) << 4))) = pk2bf(v.x, v.y);
    }
    for (int p = tid; p < BM * (CTXD / 2); p += TPB) {
        int r = p >> 7, kp = p & 127;
        f32x2 v = *(const f32x2*)(ctx + (size_t)(row0 + r) * CTXD + 2 * kp);
        *(uint32_t*)(smem + OFF_H + r * 512 + ((4 * kp) ^ ((r & 7) << 4))) = pk2bf(v.x, v.y);
    }
    if (tid < 64)  *(float*)(smem + OFF_B1 + tid * 4) = b1[tid];
    if (tid < 128) *(float*)(smem + OFF_W2 + tid * 4) = W2[(tid & 1) * 64 + (tid >> 1)];

    // ---------------- per-lane persistent constants (global scalar loads, L2-hot) ----------------
    const int ub = 32 * w + 4 * g;      // unit base; u = ub + 16*i + r
    float wdr0[2][4], wdr1[2][4], wdz0[2][4], wdz1[2][4], wdn0[2][4], wdn1[2][4], bhnc[2][4];
    float tbr[2][4], tbz[2][4], tbn[2][4], thi[2][4];
#pragma unroll
    for (int i = 0; i < 2; ++i)
#pragma unroll
        for (int r = 0; r < 4; ++r) {
            int u = ub + 16 * i + r;
            wdr0[i][r] = Wih[(size_t)u * 258 + 0];         wdr1[i][r] = Wih[(size_t)u * 258 + 1];
            wdz0[i][r] = Wih[(size_t)(128 + u) * 258 + 0]; wdz1[i][r] = Wih[(size_t)(128 + u) * 258 + 1];
            wdn0[i][r] = Wih[(size_t)(256 + u) * 258 + 0]; wdn1[i][r] = Wih[(size_t)(256 + u) * 258 + 1];
            bhnc[i][r] = bhh[256 + u];
            tbr[i][r]  = bih[u] + bhh[u];
            tbz[i][r]  = bih[128 + u] + bhh[128 + u];
            tbn[i][r]  = bih[256 + u];
            thi[i][r]  = binit[u];
        }
    float b2c0 = b2[0], b2c1 = b2[1];
    float dx[4], dy[4];
#pragma unroll
    for (int mt = 0; mt < 4; ++mt) {
        f32x2 v = *(const f32x2*)(lv + (size_t)(row0 + 16 * mt + l15) * 2);
        dx[mt] = v.x * DTC; dy[mt] = v.y * DTC;
    }

    __syncthreads();

    float b1c[4][4], w2c[4][4][2];
#pragma unroll
    for (int jt = 0; jt < 4; ++jt) {
        f32x4 bv = *(const f32x4*)(smem + OFF_B1 + (16 * jt + 4 * g) * 4);
        f32x4 wa = *(const f32x4*)(smem + OFF_W2 + (16 * jt + 4 * g) * 8);
        f32x4 wb = *(const f32x4*)(smem + OFF_W2 + (16 * jt + 4 * g) * 8 + 16);
#pragma unroll
        for (int r = 0; r < 4; ++r) b1c[jt][r] = bv[r];
        w2c[jt][0][0] = wa[0]; w2c[jt][0][1] = wa[1];
        w2c[jt][1][0] = wa[2]; w2c[jt][1][1] = wa[3];
        w2c[jt][2][0] = wb[0]; w2c[jt][2][1] = wb[1];
        w2c[jt][3][0] = wb[2]; w2c[jt][3][1] = wb[3];
    }

    // ---------------- Phase A: gi = ctx@Wihc^T (+biases), h0 = tanh(ctx@Winit^T + binit) ----------------
    // D layout [unit][row]; wave w owns units 32w..32w+31 (jl 0,1=r 2,3=z 4,5=n) + h0 units (jl 6,7)
    f32x4 zero4 = {0.f, 0.f, 0.f, 0.f};
    f32x4 accA[8][4];
#pragma unroll
    for (int jl = 0; jl < 8; ++jl)
#pragma unroll
        for (int mt = 0; mt < 4; ++mt) accA[jl][mt] = zero4;

    for (int kk = 0; kk < 8; ++kk) {            // K = 256
        short8 bf[4];
#pragma unroll
        for (int mt = 0; mt < 4; ++mt) {
            int row = 16 * mt + l15;
            bf[mt] = *(const short8*)(smem + OFF_H + row * 512 + ((64 * kk + 16 * g) ^ ((row & 7) << 4)));
        }
#pragma unroll
        for (int jl = 0; jl < 8; ++jl) {
            int jt = 8 * (jl >> 1) + 2 * w + (jl & 1);
            int u  = 16 * jt + l15;
            const float* src = (jl < 6) ? (Wih + (size_t)u * 258 + 2 + 32 * kk + 8 * g)
                                        : (Winit + (size_t)(u - 384) * 256 + 32 * kk + 8 * g);
            f32x2 v0 = *(const f32x2*)(src + 0);
            f32x2 v1 = *(const f32x2*)(src + 2);
            f32x2 v2 = *(const f32x2*)(src + 4);
            f32x2 v3 = *(const f32x2*)(src + 6);
            short8 af;
            af[0] = (short)f2bf(v0.x); af[1] = (short)f2bf(v0.y);
            af[2] = (short)f2bf(v1.x); af[3] = (short)f2bf(v1.y);
            af[4] = (short)f2bf(v2.x); af[5] = (short)f2bf(v2.y);
            af[6] = (short)f2bf(v3.x); af[7] = (short)f2bf(v3.y);
#pragma unroll
            for (int mt = 0; mt < 4; ++mt)
                accA[jl][mt] = __builtin_amdgcn_mfma_f32_16x16x32_bf16(af, bf[mt], accA[jl][mt], 0, 0, 0);
        }
    }

    f32x4 gir[2][4], giz[2][4], gin[2][4];
    float hm[2][4][4];
#pragma unroll
    for (int i = 0; i < 2; ++i)
#pragma unroll
        for (int mt = 0; mt < 4; ++mt)
#pragma unroll
            for (int r = 0; r < 4; ++r) {
                gir[i][mt][r] = accA[0 + i][mt][r] + tbr[i][r];
                giz[i][mt][r] = accA[2 + i][mt][r] + tbz[i][r];
                gin[i][mt][r] = accA[4 + i][mt][r] + tbn[i][r];
                hm[i][mt][r]  = ftanhf(accA[6 + i][mt][r] + thi[i][r]);
            }
    __syncthreads();   // all ctx reads done; hbuf region reusable

    // write h0 -> hbuf1 (acts as step "-1")
#pragma unroll
    for (int i = 0; i < 2; ++i)
#pragma unroll
        for (int mt = 0; mt < 4; ++mt)
#pragma unroll
            for (int r = 0; r < 4; ++r) {
                int u = ub + 16 * i + r;
                int row = 16 * mt + l15;
                *(unsigned short*)(smem + OFF_H + 16384 + row * 256 + ((2 * u) ^ ((row & 7) << 4))) = f2bf(hm[i][mt][r]);
            }
    __syncthreads();
    short8 hf[4][4];
#pragma unroll
    for (int mt = 0; mt < 4; ++mt)
#pragma unroll
        for (int kk = 0; kk < 4; ++kk) {
            int row = 16 * mt + l15;
            hf[mt][kk] = *(const short8*)(smem + OFF_H + 16384 + row * 256 + ((64 * kk + 16 * g) ^ ((row & 7) << 4)));
        }

    float pos[4][2];
#pragma unroll
    for (int mt = 0; mt < 4; ++mt) { pos[mt][0] = 0.f; pos[mt][1] = 0.f; }

    // ---------------- 48-step recurrence ----------------
    for (int t = 0; t < TSTEPS; ++t) {
        const int hoff = OFF_H + (t & 1) * 16384;
#pragma unroll
        for (int i = 0; i < 2; ++i) {
            f32x4 aR[4], aZ[4], aN[4];
#pragma unroll
            for (int mt = 0; mt < 4; ++mt)
#pragma unroll
                for (int r = 0; r < 4; ++r) {
                    aR[mt][r] = gir[i][mt][r] + dx[mt] * wdr0[i][r] + dy[mt] * wdr1[i][r];
                    aZ[mt][r] = giz[i][mt][r] + dx[mt] * wdz0[i][r] + dy[mt] * wdz1[i][r];
                    aN[mt][r] = bhnc[i][r];
                }
            const int uR = 16 * (2 * w + i) + l15;
            const int uZ = 16 * (8 + 2 * w + i) + l15;
            const int uN = 16 * (16 + 2 * w + i) + l15;
#pragma unroll
            for (int kk = 0; kk < 4; ++kk) {
                short8 fR = *(const short8*)(smem + OFF_WHH + uR * 256 + ((64 * kk + 16 * g) ^ ((uR & 7) << 4)));
                short8 fZ = *(const short8*)(smem + OFF_WHH + uZ * 256 + ((64 * kk + 16 * g) ^ ((uZ & 7) << 4)));
                short8 fN = *(const short8*)(smem + OFF_WHH + uN * 256 + ((64 * kk + 16 * g) ^ ((uN & 7) << 4)));
#pragma unroll
                for (int mt = 0; mt < 4; ++mt) {
                    aR[mt] = __builtin_amdgcn_mfma_f32_16x16x32_bf16(fR, hf[mt][kk], aR[mt], 0, 0, 0);
                    aZ[mt] = __builtin_amdgcn_mfma_f32_16x16x32_bf16(fZ, hf[mt][kk], aZ[mt], 0, 0, 0);
                    aN[mt] = __builtin_amdgcn_mfma_f32_16x16x32_bf16(fN, hf[mt][kk], aN[mt], 0, 0, 0);
                }
            }
            // gates (pure per-lane)
#pragma unroll
            for (int mt = 0; mt < 4; ++mt)
#pragma unroll
                for (int r = 0; r < 4; ++r) {
                    float rr  = fsigm(aR[mt][r]);
                    float zz  = fsigm(aZ[mt][r]);
                    float inn = gin[i][mt][r] + dx[mt] * wdn0[i][r] + dy[mt] * wdn1[i][r];
                    float nn  = ftanhf(fmaf(rr, aN[mt][r], inn));
                    float hp  = hm[i][mt][r];
                    float hnew = fmaf(zz, hp - nn, nn);
                    hm[i][mt][r] = hnew;
                    int u = ub + 16 * i + r;
                    int row = 16 * mt + l15;
                    *(unsigned short*)(smem + hoff + row * 256 + ((2 * u) ^ ((row & 7) << 4))) = f2bf(hnew);
                }
        }
        __syncthreads();
#pragma unroll
        for (int mt = 0; mt < 4; ++mt)
#pragma unroll
            for (int kk = 0; kk < 4; ++kk) {
                int row = 16 * mt + l15;
                hf[mt][kk] = *(const short8*)(smem + hoff + row * 256 + ((64 * kk + 16 * g) ^ ((row & 7) << 4)));
            }
        // ---- small MLP (replicated in every wave; keeps delta in-register) ----
        float pr[4][2];
#pragma unroll
        for (int mt = 0; mt < 4; ++mt) { pr[mt][0] = 0.f; pr[mt][1] = 0.f; }
#pragma unroll
        for (int jt = 0; jt < 4; ++jt) {
            f32x4 a1[4];
#pragma unroll
            for (int mt = 0; mt < 4; ++mt) a1[mt] = zero4;
            const int uW = 16 * jt + l15;
#pragma unroll
            for (int kk = 0; kk < 4; ++kk) {
                short8 wf = *(const short8*)(smem + OFF_W1 + uW * 256 + ((64 * kk + 16 * g) ^ ((uW & 7) << 4)));
#pragma unroll
                for (int mt = 0; mt < 4; ++mt)
                    a1[mt] = __builtin_amdgcn_mfma_f32_16x16x32_bf16(wf, hf[mt][kk], a1[mt], 0, 0, 0);
            }
#pragma unroll
            for (int mt = 0; mt < 4; ++mt)
#pragma unroll
                for (int r = 0; r < 4; ++r) {
                    float hv = fmaxf(a1[mt][r] + b1c[jt][r], 0.f);
                    pr[mt][0] = fmaf(hv, w2c[jt][r][0], pr[mt][0]);
                    pr[mt][1] = fmaf(hv, w2c[jt][r][1], pr[mt][1]);
                }
        }
#pragma unroll
        for (int mt = 0; mt < 4; ++mt) {
            float v0 = pr[mt][0];
            v0 += __shfl_xor(v0, 16, 64);
            v0 += __shfl_xor(v0, 32, 64);
            v0 += b2c0;
            float v1 = pr[mt][1];
            v1 += __shfl_xor(v1, 16, 64);
            v1 += __shfl_xor(v1, 32, 64);
            v1 += b2c1;
            pos[mt][0] += v0;
            pos[mt][1] += v1;
            dx[mt] = v0; dy[mt] = v1;
        }
        if (tid < 16) {
#pragma unroll
            for (int mt = 0; mt < 4; ++mt) {
                f32x2 o2; o2.x = pos[mt][0]; o2.y = pos[mt][1];
                *(f32x2*)(out + (size_t)(row0 + 16 * mt + l15) * (TSTEPS * 2) + 2 * t) = o2;
            }
        }
    }
}

extern "C" void kernel_launch(void* const* d_in, const int* in_sizes, int n_in,
                              void* d_out, int out_size, void* d_ws, size_t ws_size,
                              hipStream_t stream) {
    (void)in_sizes; (void)n_in; (void)d_ws; (void)ws_size; (void)out_size;
    const float* ctx   = (const float*)d_in[0];
    const float* lv    = (const float*)d_in[1];
    const float* Winit = (const float*)d_in[2];
    const float* binit = (const float*)d_in[3];
    const float* Wih   = (const float*)d_in[4];
    const float* bih   = (const float*)d_in[5];
    const float* Whh   = (const float*)d_in[6];
    const float* bhh   = (const float*)d_in[7];
    const float* W1    = (const float*)d_in[8];
    const float* b1    = (const float*)d_in[9];
    const float* W2    = (const float*)d_in[10];
    const float* b2    = (const float*)d_in[11];
    float* out = (float*)d_out;

    hipFuncSetAttribute(reinterpret_cast<const void*>(dd_kernel),
                        hipFuncAttributeMaxDynamicSharedMemorySize, LDS_BYTES);
    dd_kernel<<<16384 / BM, TPB, LDS_BYTES, stream>>>(
        ctx, lv, Winit, binit, Wih, bih, Whh, bhh, W1, b1, W2, b2, out);
}